// Round 4
// baseline (4382.607 us; speedup 1.0000x reference)
//
#include <hip/hip_runtime.h>
#include <math.h>

// Problem constants
#define NRT 24000   // B*N_R
#define NLT 40000   // B*N_L

static __device__ __forceinline__ float sigmoidf_(float x){ return 1.0f/(1.0f+expf(-x)); }

// bijective XCD-aware block swizzle (m204 form); nwg = gridDim.x
static __device__ __forceinline__ int xcd_swz(int bid, int nwg){
  int q = nwg>>3, r = nwg&7, x = bid&7, i = bid>>3;
  return (x<r ? x*(q+1) : r*(q+1)+(x-r)*q) + i;
}

// ---------------- input projection: out[n][c] = feat[n][0..3] @ W[4][64] + b ----------------
__global__ void k_proj(const float* __restrict__ feat, const float* __restrict__ W,
                       const float* __restrict__ bias, float* __restrict__ out, int N){
  int i = blockIdx.x*256 + threadIdx.x;
  if (i >= N*64) return;
  int n = i >> 6, c = i & 63;
  const float* f = feat + n*4;
  out[i] = fmaf(f[0], W[c], fmaf(f[1], W[64+c], fmaf(f[2], W[128+c], fmaf(f[3], W[192+c], bias[c]))));
}

// ---------------- per-group (16 voxels) merged neighbor-k bitmask ----------------
__global__ void k_kmask16(const int* __restrict__ nbr, int NG, int* __restrict__ kmask){
  int g = blockIdx.x*64 + threadIdx.x;
  if (g >= NG) return;
  int m = 0;
  for (int v=0;v<16;v++){
    const int* row = nbr + (size_t)(g*16+v)*27;
    for (int k=0;k<27;k++) if (row[k] >= 0) m |= (1<<k);
  }
  kmask[g] = m;
}

// ---------------- sconv weight repack: WcT[lc][k][c4][d][j] = Wconv[lc][k][4*c4+j][d] ----------------
// (interleaved layout: per-slice, 16 coalesced dwordx4 loads give lane d its column)
__global__ void k_wc(const float* __restrict__ Wconv, float* __restrict__ WcT){
  int i = blockIdx.x*256+threadIdx.x; // total 12*27*16*64*4 = 1327104
  if (i >= 12*27*16*64*4) return;
  int j = i & 3; int r = i >> 2;
  int d = r & 63; r >>= 6;
  int c4 = r & 15; r >>= 4;
  int k = r % 27; int lc = r / 27;
  WcT[i] = Wconv[(size_t)lc*110592 + (size_t)k*4096 + (size_t)(4*c4+j)*64 + d];
}

// ---------------- sparse 27-pt conv: one wave per 16 voxels, weight column in VGPRs per k ----------------
// out[n][d] = sum_k sum_c f[nbr[n][k]][c] * W[k][c][d]
// (bconv skipped: per-channel constant shift cancels exactly in the following BN)
__global__ void k_sconv(const float* __restrict__ fin, const int* __restrict__ nbr,
                        const int* __restrict__ kmask, const float* __restrict__ W, // WcT block
                        float* __restrict__ fout, int N){
  int t = threadIdx.x & 63;
  int blk = xcd_swz(blockIdx.x, gridDim.x);
  int g = blk*4 + (threadIdx.x>>6);      // group index (16 voxels per wave)
  int n0 = g*16;
  float acc[16];
  #pragma unroll
  for (int v=0;v<16;v++) acc[v] = 0.f;
  const int* nrow = nbr + (size_t)n0*27;
  int m = kmask[g];
  while (m){
    int k = __builtin_ctz(m); m &= m-1;
    const float4* w4 = reinterpret_cast<const float4*>(W) + k*1024 + t;
    float4 wreg[16];
    #pragma unroll
    for (int c4=0;c4<16;c4++) wreg[c4] = w4[c4*64];   // coalesced; held in VGPRs, reused 16x
    #pragma unroll
    for (int v=0;v<16;v++){
      int nb = nrow[27*v + k];           // wave-uniform
      if (nb >= 0){
        const float4* fr = reinterpret_cast<const float4*>(fin + (size_t)nb*64);
        float4 a = make_float4(0.f,0.f,0.f,0.f);
        #pragma unroll
        for (int c4=0;c4<16;c4++){
          float4 fv = fr[c4];            // uniform broadcast
          a.x = fmaf(fv.x, wreg[c4].x, a.x);
          a.y = fmaf(fv.y, wreg[c4].y, a.y);
          a.z = fmaf(fv.z, wreg[c4].z, a.z);
          a.w = fmaf(fv.w, wreg[c4].w, a.w);
        }
        acc[v] += (a.x+a.y)+(a.z+a.w);
      }
    }
  }
  #pragma unroll
  for (int v=0;v<16;v++) fout[(size_t)(n0+v)*64 + t] = acc[v];
}

// ---------------- per-channel sum/sumsq partials over N rows (deterministic) ----------------
__global__ void k_colsum(const float* __restrict__ f, int N, float* __restrict__ partial){
  int d = threadIdx.x & 63, sub = threadIdx.x >> 6;
  float s=0.f, s2=0.f;
  for (int n = blockIdx.x*4 + sub; n < N; n += 1024){
    float v = f[(size_t)n*64+d];
    s += v; s2 = fmaf(v,v,s2);
  }
  __shared__ float ls[4][64], ls2[4][64];
  ls[sub][d]=s; ls2[sub][d]=s2;
  __syncthreads();
  if (sub==0){
    s  = ls[0][d]+ls[1][d]+ls[2][d]+ls[3][d];
    s2 = ls2[0][d]+ls2[1][d]+ls2[2][d]+ls2[3][d];
    partial[(blockIdx.x*64+d)*2+0]=s;
    partial[(blockIdx.x*64+d)*2+1]=s2;
  }
}

__global__ void k_bnfin(const float* __restrict__ partial, int nblk, float invN,
                        const float* __restrict__ g, const float* __restrict__ b,
                        float* __restrict__ mv){
  int d = threadIdx.x; // 64
  float s=0.f, s2=0.f;
  for (int i=0;i<nblk;i++){ s += partial[(i*64+d)*2]; s2 += partial[(i*64+d)*2+1]; }
  float mean = s*invN;
  float var  = s2*invN - mean*mean;
  float rstd = 1.0f/sqrtf(var + 1e-5f);
  float sc = g[d]*rstd;
  mv[d*2]   = sc;
  mv[d*2+1] = b[d] - mean*sc;
}

__global__ void k_bnrelu(float* __restrict__ f, const float* __restrict__ mv, int total){
  int i = blockIdx.x*256+threadIdx.x;
  if (i>=total) return;
  int c = i & 63;
  float v = fmaf(f[i], mv[c*2], mv[c*2+1]);
  f[i] = v>0.f? v:0.f;
}

// ---------------- imgf[b][c] = sigmoid(img[b] @ Wimg + bimg) ----------------
__global__ void k_imgf(const float* __restrict__ img, const float* __restrict__ Wimg,
                       const float* __restrict__ bimg, float* __restrict__ imgf){
  int t = threadIdx.x; // 128
  int b = t>>6, c = t&63;
  float s = bimg[c];
  const float* ir = img + b*512;
  for (int j=0;j<512;j++) s = fmaf(ir[j], Wimg[j*64+c], s);
  imgf[b*64+c] = sigmoidf_(s);
}

// ---------------- attention + gate, in-place update of fL ----------------
// fused = (sum_k a_k key_k) @ Wval + bval   (softmax weights sum to 1)
__global__ void k_attn(float* __restrict__ fL, const float* __restrict__ fR,
                       const int* __restrict__ knn, const int* __restrict__ coordsL,
                       const float* __restrict__ Wval, const float* __restrict__ bval,
                       const float* __restrict__ Wgate, const float* __restrict__ bgate,
                       const float* __restrict__ imgf, int K){
  __shared__ float keys[64*65];   // padded stride 65 -> conflict-free both axes
  __shared__ float fls[64];
  __shared__ float aw[64];
  __shared__ float wks[64];
  __shared__ float fus[64];
  int n = blockIdx.x, t = threadIdx.x;
  float fl = fL[(size_t)n*64+t];
  fls[t] = fl;
  const int* kn = knn + (size_t)n*K;
  for (int k=0;k<K;k++){
    int r = kn[k];
    keys[k*65+t] = fR[(size_t)r*64+t];
  }
  __syncthreads();
  float s = -1e30f;
  if (t < K){
    const float* kr = keys + t*65;
    float a0 = 0.f;
    #pragma unroll
    for (int c=0;c<64;c++) a0 = fmaf(fls[c], kr[c], a0);
    s = a0;
  }
  float mx = s;
  #pragma unroll
  for (int m=32;m;m>>=1) mx = fmaxf(mx, __shfl_xor(mx, m, 64));
  float e = (t<K) ? expf(s-mx) : 0.f;
  float se = e;
  #pragma unroll
  for (int m=32;m;m>>=1) se += __shfl_xor(se, m, 64);
  aw[t] = e/se;
  __syncthreads();
  float wk = 0.f;
  for (int k=0;k<K;k++) wk = fmaf(aw[k], keys[k*65+t], wk);
  wks[t] = wk;
  __syncthreads();
  float fu = bval[t];
  #pragma unroll
  for (int c=0;c<64;c++) fu = fmaf(wks[c], Wval[c*64+t], fu);
  int bid = coordsL[n*4];
  fu *= imgf[bid*64+t];
  fus[t] = fu;
  __syncthreads();
  float gs = bgate[t];
  #pragma unroll
  for (int c=0;c<64;c++) gs = fmaf(fls[c], Wgate[c*64+t], gs);
  #pragma unroll
  for (int c=0;c<64;c++) gs = fmaf(fus[c], Wgate[(64+c)*64+t], gs);
  float gate = sigmoidf_(gs);
  fL[(size_t)n*64+t] = fl + gate*fu;
}

// ---------------- voxel index grid: grid[b][y][x][z] = row or -1 ----------------
__global__ void k_grid(const int* __restrict__ coords, int N, int* __restrict__ grid){
  int n = blockIdx.x*256+threadIdx.x;
  if (n>=N) return;
  int b=coords[n*4], z=coords[n*4+1], y=coords[n*4+2], x=coords[n*4+3];
  grid[((b*128+y)*128+x)*16+z] = n;
}

// ---------------- compact per-column (b,y,x) voxel lists (deterministic z order) ----------------
__global__ void k_colbuild(const int* __restrict__ grid, int* __restrict__ ccnt,
                           int* __restrict__ cent){
  int col = blockIdx.x*256+threadIdx.x;
  if (col >= 2*128*128) return;
  const int* g = grid + col*16;
  int c=0;
  for (int z=0;z<16;z++){ int v=g[z]; if (v>=0) cent[col*16 + (c++)] = (v<<4)|z; }
  ccnt[col]=c;
}

// ---------------- z-grouped voxel lists (slot order irrelevant: tmp indexed by voxel id) ----------------
__global__ void k_zlist(const int* __restrict__ coords, int N, int* __restrict__ zcnt,
                        int* __restrict__ zlist, int zcap){
  int n = blockIdx.x*256+threadIdx.x;
  if (n>=N) return;
  int z = coords[n*4+1];
  int slot = atomicAdd(&zcnt[z], 1);
  zlist[z*zcap + slot] = n;
}

// ---------------- BEV weight repack: Wt3[ls][q][z][c4][o][j] = Wbev[ls][(4c4+j)*16+z][o][2-q/3][2-q%3] ----------------
__global__ void k_wt3(const float* __restrict__ Wbev, float* __restrict__ Wt3){
  int i = blockIdx.x*256+threadIdx.x; // total 4*9*16*16*64*4 = 2359296
  if (i >= 4*9*16*16*64*4) return;
  int j = i & 3; int r = i >> 2;
  int o = r & 63; r >>= 6;
  int c4 = r & 15; r >>= 4;
  int z = r & 15; r >>= 4;
  int q = r % 9; int ls = r / 9;
  int c = 4*c4 + j;
  int ky = 2-q/3, kx = 2-q%3;      // = 1-dy, 1-dx
  Wt3[i] = Wbev[(size_t)ls*589824 + (size_t)(c*16+z)*576 + o*9 + ky*3 + kx];
}

// ---------------- BEV stage 1: per-(q,z) GEMM into tmp[v][q][o] ----------------
// wave owns (q,z): weight column in 64 VGPRs, streams voxels of zlist[z]
__global__ void k_bevg(const float* __restrict__ f, const int* __restrict__ zcnt,
                       const int* __restrict__ zlist, int zcap,
                       const float* __restrict__ Wt,  // [9][16][16][64][4]
                       float* __restrict__ tmp, int CH){
  int task = blockIdx.x / CH, chunk = blockIdx.x % CH;
  int q = task >> 4, z = task & 15;
  int t = threadIdx.x;   // 64
  const float4* w4 = reinterpret_cast<const float4*>(Wt + (size_t)(((q<<4)+z)<<12)) + t;
  float4 wreg[16];
  #pragma unroll
  for (int c4=0;c4<16;c4++) wreg[c4] = w4[c4*64];
  int cnt = zcnt[z];
  const int* zl = zlist + z*zcap;
  for (int i=chunk; i<cnt; i+=CH){
    int v = zl[i];
    const float4* fr = reinterpret_cast<const float4*>(f + (size_t)v*64);
    float4 a = make_float4(0.f,0.f,0.f,0.f);
    #pragma unroll
    for (int c4=0;c4<16;c4++){
      float4 fv = fr[c4];
      a.x = fmaf(fv.x, wreg[c4].x, a.x);
      a.y = fmaf(fv.y, wreg[c4].y, a.y);
      a.z = fmaf(fv.z, wreg[c4].z, a.z);
      a.w = fmaf(fv.w, wreg[c4].w, a.w);
    }
    tmp[((size_t)v*9+q)*64 + t] = (a.x+a.y)+(a.z+a.w);
  }
}

// ---------------- BEV stage 2: gather tmp into output (1x4 pixel strip per wave) ----------------
// (bbev skipped: per-channel constant cancels in the following BN over (b,y,x))
__global__ void k_bevs(const float* __restrict__ tmp, const int* __restrict__ ccnt,
                       const int* __restrict__ cent, float* __restrict__ outp){
  int blk = xcd_swz(blockIdx.x, gridDim.x);  // 8192 blocks
  int b = blk>>12; int rem = blk&4095; int y = rem>>5; int x0 = (rem&31)<<2;
  int t = threadIdx.x;
  float acc[4] = {0.f,0.f,0.f,0.f};
  #pragma unroll
  for (int dy=-1;dy<=1;dy++){
    int y2 = y+dy;
    if ((unsigned)y2 >= 128u) continue;
    int qb = (dy+1)*3 + 1;
    for (int cx=x0-1; cx<=x0+4; cx++){
      if ((unsigned)cx >= 128u) continue;
      int col = ((b<<7)+y2)*128 + cx;
      int cn = ccnt[col];
      const int* ce = cent + col*16;
      int d0 = cx - x0;
      for (int i=0;i<cn;i++){
        int rid = ce[i]>>4;                 // wave-uniform
        const float* tb = tmp + (size_t)rid*576 + qb*64 + t;
        #pragma unroll
        for (int v=0;v<4;v++){
          int dx = d0 - v;
          if (dx>=-1 && dx<=1) acc[v] += tb[dx*64];
        }
      }
    }
  }
  float4 o4 = make_float4(acc[0],acc[1],acc[2],acc[3]);
  // out elements (b, slab*64 + t, y, x0..x0+3); outp already offset by slab*64*16384
  *reinterpret_cast<float4*>(outp + (size_t)b*(256*16384) + (size_t)t*16384 + y*128 + x0) = o4;
}

// ---------------- BEV BN stats (one block per channel) + apply ----------------
__global__ void k_bevstat(const float* __restrict__ outp, const float* __restrict__ g,
                          const float* __restrict__ b, float* __restrict__ mv){
  int ch = blockIdx.x, t = threadIdx.x; // 64 blocks x 256 threads
  float s=0.f, s2=0.f;
  for (int bb=0;bb<2;bb++){
    const float* base = outp + (size_t)bb*(256*16384) + (size_t)ch*16384;
    for (int p=t;p<16384;p+=256){ float v = base[p]; s+=v; s2=fmaf(v,v,s2); }
  }
  __shared__ float ls[256], ls2[256];
  ls[t]=s; ls2[t]=s2; __syncthreads();
  for (int m=128;m;m>>=1){ if (t<m){ ls[t]+=ls[t+m]; ls2[t]+=ls2[t+m]; } __syncthreads(); }
  if (t==0){
    float mean = ls[0]*(1.0f/32768.0f);
    float var  = ls2[0]*(1.0f/32768.0f) - mean*mean;
    float rstd = 1.0f/sqrtf(var+1e-5f);
    float sc = g[ch]*rstd;
    mv[ch*2]=sc; mv[ch*2+1]=b[ch]-mean*sc;
  }
}

__global__ void k_bevbn(float* __restrict__ outp, const float* __restrict__ mv){
  int i = blockIdx.x*256+threadIdx.x; // 2*64*16384
  if (i >= 2*64*16384) return;
  int bb = i>>20; int r = i & ((1<<20)-1);
  int ch = r>>14; int p = r&16383;
  float* a = outp + (size_t)bb*(256*16384) + (size_t)ch*16384 + p;
  float v = fmaf(*a, mv[ch*2], mv[ch*2+1]);
  *a = v>0.f? v:0.f;
}

extern "C" void kernel_launch(void* const* d_in, const int* in_sizes, int n_in,
                              void* d_out, int out_size, void* d_ws, size_t ws_size,
                              hipStream_t stream){
  const float* featR = (const float*)d_in[0];
  const float* featL = (const float*)d_in[1];
  const float* img   = (const float*)d_in[2];
  const float* Win   = (const float*)d_in[3];
  const float* bin_  = (const float*)d_in[4];
  const float* Wconv = (const float*)d_in[5];
  // d_in[6] bconv: cancels in BN
  const float* bng   = (const float*)d_in[7];
  const float* bnb   = (const float*)d_in[8];
  const float* Wimg  = (const float*)d_in[9];
  const float* bimg  = (const float*)d_in[10];
  const float* Wval  = (const float*)d_in[11];
  const float* bval  = (const float*)d_in[12];
  const float* Wgate = (const float*)d_in[13];
  const float* bgate = (const float*)d_in[14];
  const float* Wbev  = (const float*)d_in[15];
  // d_in[16] bbev: cancels in BN
  const float* bntg  = (const float*)d_in[17];
  const float* bntb  = (const float*)d_in[18];
  const int* nbrR    = (const int*)d_in[19];
  const int* nbrL    = (const int*)d_in[20];
  const int* knn0    = (const int*)d_in[21];
  const int* knn1    = (const int*)d_in[22];
  const int* coordsR = (const int*)d_in[23];
  const int* coordsL = (const int*)d_in[24];
  float* outp = (float*)d_out;

  // workspace carve-out (~155 MB)
  char* w = (char*)d_ws;
  auto alloc = [&](size_t bytes){ char* p = w; w += (bytes + 255) & ~(size_t)255; return p; };
  float* fRa = (float*)alloc((size_t)NRT*64*4);
  float* fRb = (float*)alloc((size_t)NRT*64*4);
  float* fLa = (float*)alloc((size_t)NLT*64*4);
  float* fLb = (float*)alloc((size_t)NLT*64*4);
  int*   gridR = (int*)alloc((size_t)2*128*128*16*4);
  int*   gridL = (int*)alloc((size_t)2*128*128*16*4);
  float* Wt3 = (float*)alloc((size_t)4*9*16*16*64*4*4);
  float* WcT = (float*)alloc((size_t)12*27*16*64*4*4);
  float* imgfbuf = (float*)alloc(2*64*4);
  float* partial = (float*)alloc((size_t)256*64*2*4);
  float* mv = (float*)alloc(64*2*4);
  int* kmaskR = (int*)alloc((size_t)(NRT/16)*4);
  int* kmaskL = (int*)alloc((size_t)(NLT/16)*4);
  int* ccntR = (int*)alloc((size_t)2*128*128*4);
  int* ccntL = (int*)alloc((size_t)2*128*128*4);
  int* centR = (int*)alloc((size_t)2*128*128*16*4);
  int* centL = (int*)alloc((size_t)2*128*128*16*4);
  int* zcnt  = (int*)alloc(32*4);                 // [0..15]=R, [16..31]=L
  int* zlistR = (int*)alloc((size_t)16*NRT*4);
  int* zlistL = (int*)alloc((size_t)16*NLT*4);
  float* tmp = (float*)alloc((size_t)NLT*576*4);  // 92 MB, reused R/L sequentially

  hipMemsetAsync(gridR, 0xFF, (size_t)2*128*128*16*4, stream);
  hipMemsetAsync(gridL, 0xFF, (size_t)2*128*128*16*4, stream);
  hipMemsetAsync(zcnt, 0, 32*4, stream);
  k_grid<<<(NRT+255)/256,256,0,stream>>>(coordsR, NRT, gridR);
  k_grid<<<(NLT+255)/256,256,0,stream>>>(coordsL, NLT, gridL);
  k_colbuild<<<(2*128*128+255)/256,256,0,stream>>>(gridR, ccntR, centR);
  k_colbuild<<<(2*128*128+255)/256,256,0,stream>>>(gridL, ccntL, centL);
  k_zlist<<<(NRT+255)/256,256,0,stream>>>(coordsR, NRT, zcnt,    zlistR, NRT);
  k_zlist<<<(NLT+255)/256,256,0,stream>>>(coordsL, NLT, zcnt+16, zlistL, NLT);
  k_kmask16<<<((NRT/16)+63)/64,64,0,stream>>>(nbrR, NRT/16, kmaskR);
  k_kmask16<<<((NLT/16)+63)/64,64,0,stream>>>(nbrL, NLT/16, kmaskL);
  k_wt3<<<(4*9*16*16*64*4+255)/256,256,0,stream>>>(Wbev, Wt3);
  k_wc<<<(12*27*16*64*4+255)/256,256,0,stream>>>(Wconv, WcT);

  k_proj<<<(NRT*64+255)/256,256,0,stream>>>(featR, Win,     bin_,    fRa, NRT);
  k_proj<<<(NLT*64+255)/256,256,0,stream>>>(featL, Win+256, bin_+64, fLa, NLT);

  const int CH = 32;   // chunks per (q,z) task in k_bevg
  float* fRcur=fRa; float* fRalt=fRb; float* fLcur=fLa; float* fLalt=fLb;
  for (int l=0;l<2;l++){
    // branch R: 3 x (sconv -> BN stats -> bn+relu)
    for (int j=0;j<3;j++){
      const float* Wc = WcT + (size_t)((l*2+0)*3+j)*110592;
      k_sconv<<<NRT/64,256,0,stream>>>(fRcur, nbrR, kmaskR, Wc, fRalt, NRT);
      k_colsum<<<256,256,0,stream>>>(fRalt, NRT, partial);
      k_bnfin<<<1,64,0,stream>>>(partial, 256, 1.0f/NRT,
                                 bng + ((l*2+0)*3+j)*64, bnb + ((l*2+0)*3+j)*64, mv);
      k_bnrelu<<<(NRT*64+255)/256,256,0,stream>>>(fRalt, mv, NRT*64);
      float* tmpp=fRcur; fRcur=fRalt; fRalt=tmpp;
    }
    // branch L
    for (int j=0;j<3;j++){
      const float* Wc = WcT + (size_t)((l*2+1)*3+j)*110592;
      k_sconv<<<NLT/64,256,0,stream>>>(fLcur, nbrL, kmaskL, Wc, fLalt, NLT);
      k_colsum<<<256,256,0,stream>>>(fLalt, NLT, partial);
      k_bnfin<<<1,64,0,stream>>>(partial, 256, 1.0f/NLT,
                                 bng + ((l*2+1)*3+j)*64, bnb + ((l*2+1)*3+j)*64, mv);
      k_bnrelu<<<(NLT*64+255)/256,256,0,stream>>>(fLalt, mv, NLT*64);
      float* tmpp=fLcur; fLcur=fLalt; fLalt=tmpp;
    }
    // image gate features for this layer
    k_imgf<<<1,128,0,stream>>>(img, Wimg + (size_t)l*512*64, bimg + l*64, imgfbuf);
    // attention + gated residual (in-place on fL)
    const int* knn = (l==0)? knn0 : knn1;
    int K = (l==0)? 64 : 32;
    k_attn<<<NLT,64,0,stream>>>(fLcur, fRcur, knn, coordsL,
                                Wval + (size_t)l*4096, bval + l*64,
                                Wgate + (size_t)l*8192, bgate + l*64,
                                imgfbuf, K);
    // BEV R (slab 2l) and BEV L (slab 2l+1)
    {
      float* op = outp + (size_t)(2*l)*64*16384;
      const float* wt = Wt3 + (size_t)(l*2+0)*589824;
      k_bevg<<<144*CH,64,0,stream>>>(fRcur, zcnt,    zlistR, NRT, wt, tmp, CH);
      k_bevs<<<2*128*32,64,0,stream>>>(tmp, ccntR, centR, op);
      k_bevstat<<<64,256,0,stream>>>(op, bntg + (l*2+0)*64, bntb + (l*2+0)*64, mv);
      k_bevbn<<<(2*64*16384+255)/256,256,0,stream>>>(op, mv);
    }
    {
      float* op = outp + (size_t)(2*l+1)*64*16384;
      const float* wt = Wt3 + (size_t)(l*2+1)*589824;
      k_bevg<<<144*CH,64,0,stream>>>(fLcur, zcnt+16, zlistL, NLT, wt, tmp, CH);
      k_bevs<<<2*128*32,64,0,stream>>>(tmp, ccntL, centL, op);
      k_bevstat<<<64,256,0,stream>>>(op, bntg + (l*2+1)*64, bntb + (l*2+1)*64, mv);
      k_bevbn<<<(2*64*16384+255)/256,256,0,stream>>>(op, mv);
    }
  }
}

// Round 5
// 3265.983 us; speedup vs baseline: 1.3419x; 1.3419x over previous
//
#include <hip/hip_runtime.h>
#include <math.h>

// Problem constants
#define NRT 24000   // B*N_R
#define NLT 40000   // B*N_L

static __device__ __forceinline__ float sigmoidf_(float x){ return 1.0f/(1.0f+expf(-x)); }

// bijective XCD-aware block swizzle (m204 form); nwg = gridDim.x
static __device__ __forceinline__ int xcd_swz(int bid, int nwg){
  int q = nwg>>3, r = nwg&7, x = bid&7, i = bid>>3;
  return (x<r ? x*(q+1) : r*(q+1)+(x-r)*q) + i;
}

// ---------------- input projection: out[n][c] = feat[n][0..3] @ W[4][64] + b ----------------
__global__ void k_proj(const float* __restrict__ feat, const float* __restrict__ W,
                       const float* __restrict__ bias, float* __restrict__ out, int N){
  int i = blockIdx.x*256 + threadIdx.x;
  if (i >= N*64) return;
  int n = i >> 6, c = i & 63;
  const float* f = feat + n*4;
  out[i] = fmaf(f[0], W[c], fmaf(f[1], W[64+c], fmaf(f[2], W[128+c], fmaf(f[3], W[192+c], bias[c]))));
}

// ---------------- per-group (16 voxels) merged neighbor-k bitmask ----------------
__global__ void k_kmask16(const int* __restrict__ nbr, int NG, int* __restrict__ kmask){
  int g = blockIdx.x*64 + threadIdx.x;
  if (g >= NG) return;
  int m = 0;
  for (int v=0;v<16;v++){
    const int* row = nbr + (size_t)(g*16+v)*27;
    for (int k=0;k<27;k++) if (row[k] >= 0) m |= (1<<k);
  }
  kmask[g] = m;
}

// ---------------- sconv weight repack: WcT[lc][k][c4][d][j] = Wconv[lc][k][4*c4+j][d] ----------------
__global__ void k_wc(const float* __restrict__ Wconv, float* __restrict__ WcT){
  int i = blockIdx.x*256+threadIdx.x; // total 12*27*16*64*4 = 1327104
  if (i >= 12*27*16*64*4) return;
  int j = i & 3; int r = i >> 2;
  int d = r & 63; r >>= 6;
  int c4 = r & 15; r >>= 4;
  int k = r % 27; int lc = r / 27;
  WcT[i] = Wconv[(size_t)lc*110592 + (size_t)k*4096 + (size_t)(4*c4+j)*64 + d];
}

// ---------------- sparse 27-pt conv: block = 16 voxels; 4 waves own disjoint k-ranges ----------------
// partial[s][n][d] = sum_{k in range s} sum_c f[nbr[n][k]][c] * W[k][c][d]
// (bconv skipped: per-channel constant shift cancels exactly in the following BN)
__global__ void k_sconv(const float* __restrict__ fin, const int* __restrict__ nbr,
                        const int* __restrict__ kmask, const float* __restrict__ W, // WcT block
                        float* __restrict__ psum, size_t pstride, int N){
  int t = threadIdx.x & 63;
  int sub = threadIdx.x >> 6;            // k-split 0..3
  int g = xcd_swz(blockIdx.x, gridDim.x);// voxel group (16 voxels)
  int n0 = g*16;
  float acc[16];
  #pragma unroll
  for (int v=0;v<16;v++) acc[v] = 0.f;
  const int* nrow = nbr + (size_t)n0*27;
  int m = kmask[g] & (0x7F << (7*sub));  // bits 27..31 never set
  while (m){
    int k = __builtin_ctz(m); m &= m-1;
    const float4* w4 = reinterpret_cast<const float4*>(W) + k*1024 + t;
    float4 wreg[16];
    #pragma unroll
    for (int c4=0;c4<16;c4++) wreg[c4] = w4[c4*64];   // coalesced; reused across visits
    #pragma unroll
    for (int v=0;v<16;v++){
      int nb = nrow[27*v + k];           // wave-uniform
      if (nb >= 0){
        const float4* fr = reinterpret_cast<const float4*>(fin + (size_t)nb*64);
        float4 a = make_float4(0.f,0.f,0.f,0.f);
        #pragma unroll
        for (int c4=0;c4<16;c4++){
          float4 fv = fr[c4];            // uniform broadcast
          a.x = fmaf(fv.x, wreg[c4].x, a.x);
          a.y = fmaf(fv.y, wreg[c4].y, a.y);
          a.z = fmaf(fv.z, wreg[c4].z, a.z);
          a.w = fmaf(fv.w, wreg[c4].w, a.w);
        }
        acc[v] += (a.x+a.y)+(a.z+a.w);
      }
    }
  }
  float* po = psum + (size_t)sub*pstride;
  #pragma unroll
  for (int v=0;v<16;v++) po[(size_t)(n0+v)*64 + t] = acc[v];
}

// ---------------- per-channel sum/sumsq partials over 4-way psum (deterministic) ----------------
__global__ void k_colsum4(const float* __restrict__ p, size_t st, int N,
                          float* __restrict__ partial){
  int d = threadIdx.x & 63, sub = threadIdx.x >> 6;
  float s=0.f, s2=0.f;
  for (int n = blockIdx.x*4 + sub; n < N; n += 1024){
    size_t i = (size_t)n*64+d;
    float v = p[i] + p[i+st] + p[i+2*st] + p[i+3*st];
    s += v; s2 = fmaf(v,v,s2);
  }
  __shared__ float ls[4][64], ls2[4][64];
  ls[sub][d]=s; ls2[sub][d]=s2;
  __syncthreads();
  if (sub==0){
    s  = ls[0][d]+ls[1][d]+ls[2][d]+ls[3][d];
    s2 = ls2[0][d]+ls2[1][d]+ls2[2][d]+ls2[3][d];
    partial[(blockIdx.x*64+d)*2+0]=s;
    partial[(blockIdx.x*64+d)*2+1]=s2;
  }
}

__global__ void k_bnfin(const float* __restrict__ partial, int nblk, float invN,
                        const float* __restrict__ g, const float* __restrict__ b,
                        float* __restrict__ mv){
  int t = threadIdx.x, d = t & 63, sub = t >> 6; // 256 threads
  float s=0.f, s2=0.f;
  for (int i=sub;i<nblk;i+=4){ s += partial[(i*64+d)*2]; s2 += partial[(i*64+d)*2+1]; }
  __shared__ float ls[4][64], ls2[4][64];
  ls[sub][d]=s; ls2[sub][d]=s2;
  __syncthreads();
  if (sub==0){
    s  = ls[0][d]+ls[1][d]+ls[2][d]+ls[3][d];
    s2 = ls2[0][d]+ls2[1][d]+ls2[2][d]+ls2[3][d];
    float mean = s*invN;
    float var  = s2*invN - mean*mean;
    float rstd = 1.0f/sqrtf(var + 1e-5f);
    float sc = g[d]*rstd;
    mv[d*2]   = sc;
    mv[d*2+1] = b[d] - mean*sc;
  }
}

// ---------------- fused 4-way add + BN + relu: fout = relu(bn(sum psum)) ----------------
__global__ void k_bnrelu4(const float* __restrict__ p, size_t st,
                          const float* __restrict__ mv, float* __restrict__ fout, int total){
  int i = blockIdx.x*256+threadIdx.x;
  if (i>=total) return;
  int c = i & 63;
  float s = p[i] + p[i+st] + p[i+2*st] + p[i+3*st];
  float v = fmaf(s, mv[c*2], mv[c*2+1]);
  fout[i] = v>0.f? v:0.f;
}

// ---------------- imgf[b][c] = sigmoid(img[b] @ Wimg + bimg) ----------------
__global__ void k_imgf(const float* __restrict__ img, const float* __restrict__ Wimg,
                       const float* __restrict__ bimg, float* __restrict__ imgf){
  int t = threadIdx.x; // 128
  int b = t>>6, c = t&63;
  float s = bimg[c];
  const float* ir = img + b*512;
  for (int j=0;j<512;j++) s = fmaf(ir[j], Wimg[j*64+c], s);
  imgf[b*64+c] = sigmoidf_(s);
}

// ---------------- attention + gate, in-place update of fL ----------------
// fused = (sum_k a_k key_k) @ Wval + bval   (softmax weights sum to 1)
__global__ void k_attn(float* __restrict__ fL, const float* __restrict__ fR,
                       const int* __restrict__ knn, const int* __restrict__ coordsL,
                       const float* __restrict__ Wval, const float* __restrict__ bval,
                       const float* __restrict__ Wgate, const float* __restrict__ bgate,
                       const float* __restrict__ imgf, int K){
  __shared__ float keys[64*65];   // padded stride 65 -> conflict-free both axes
  __shared__ float fls[64];
  __shared__ float aw[64];
  __shared__ float wks[64];
  __shared__ float fus[64];
  int n = blockIdx.x, t = threadIdx.x;
  float fl = fL[(size_t)n*64+t];
  fls[t] = fl;
  const int* kn = knn + (size_t)n*K;
  for (int k=0;k<K;k++){
    int r = kn[k];
    keys[k*65+t] = fR[(size_t)r*64+t];
  }
  __syncthreads();
  float s = -1e30f;
  if (t < K){
    const float* kr = keys + t*65;
    float a0 = 0.f;
    #pragma unroll
    for (int c=0;c<64;c++) a0 = fmaf(fls[c], kr[c], a0);
    s = a0;
  }
  float mx = s;
  #pragma unroll
  for (int m=32;m;m>>=1) mx = fmaxf(mx, __shfl_xor(mx, m, 64));
  float e = (t<K) ? expf(s-mx) : 0.f;
  float se = e;
  #pragma unroll
  for (int m=32;m;m>>=1) se += __shfl_xor(se, m, 64);
  aw[t] = e/se;
  __syncthreads();
  float wk = 0.f;
  for (int k=0;k<K;k++) wk = fmaf(aw[k], keys[k*65+t], wk);
  wks[t] = wk;
  __syncthreads();
  float fu = bval[t];
  #pragma unroll
  for (int c=0;c<64;c++) fu = fmaf(wks[c], Wval[c*64+t], fu);
  int bid = coordsL[n*4];
  fu *= imgf[bid*64+t];
  fus[t] = fu;
  __syncthreads();
  float gs = bgate[t];
  #pragma unroll
  for (int c=0;c<64;c++) gs = fmaf(fls[c], Wgate[c*64+t], gs);
  #pragma unroll
  for (int c=0;c<64;c++) gs = fmaf(fus[c], Wgate[(64+c)*64+t], gs);
  float gate = sigmoidf_(gs);
  fL[(size_t)n*64+t] = fl + gate*fu;
}

// ---------------- voxel index grid: grid[b][y][x][z] = row or -1 ----------------
__global__ void k_grid(const int* __restrict__ coords, int N, int* __restrict__ grid){
  int n = blockIdx.x*256+threadIdx.x;
  if (n>=N) return;
  int b=coords[n*4], z=coords[n*4+1], y=coords[n*4+2], x=coords[n*4+3];
  grid[((b*128+y)*128+x)*16+z] = n;
}

// ---------------- compact per-column (b,y,x) voxel lists (deterministic z order) ----------------
__global__ void k_colbuild(const int* __restrict__ grid, int* __restrict__ ccnt,
                           int* __restrict__ cent){
  int col = blockIdx.x*256+threadIdx.x;
  if (col >= 2*128*128) return;
  const int* g = grid + col*16;
  int c=0;
  for (int z=0;z<16;z++){ int v=g[z]; if (v>=0) cent[col*16 + (c++)] = (v<<4)|z; }
  ccnt[col]=c;
}

// ---------------- (b,z) bucket boundaries: coords sorted by (b,z,y,x) => contiguous ranges ----------------
// zs[key] = first row with bucket >= key; zs[32] = N. key = b*16+z.
__global__ void k_zbound(const int* __restrict__ coords, int N, int* __restrict__ zs){
  int n = blockIdx.x*256+threadIdx.x;
  if (n>=N) return;
  int key = coords[n*4]*16 + coords[n*4+1];
  int pk = (n>0) ? coords[(n-1)*4]*16 + coords[(n-1)*4+1] : -1;
  for (int kk=pk+1; kk<=key; kk++) zs[kk] = n;
  if (n==N-1){ for (int kk=key+1; kk<=32; kk++) zs[kk] = N; }
}

// ---------------- BEV weight repack: Wt3[ls][q][z][c4][o][j] = Wbev[ls][(4c4+j)*16+z][o][2-q/3][2-q%3] ----------------
__global__ void k_wt3(const float* __restrict__ Wbev, float* __restrict__ Wt3){
  int i = blockIdx.x*256+threadIdx.x; // total 4*9*16*16*64*4 = 2359296
  if (i >= 4*9*16*16*64*4) return;
  int j = i & 3; int r = i >> 2;
  int o = r & 63; r >>= 6;
  int c4 = r & 15; r >>= 4;
  int z = r & 15; r >>= 4;
  int q = r % 9; int ls = r / 9;
  int c = 4*c4 + j;
  int ky = 2-q/3, kx = 2-q%3;      // = 1-dy, 1-dx
  Wt3[i] = Wbev[(size_t)ls*589824 + (size_t)(c*16+z)*576 + o*9 + ky*3 + kx];
}

// ---------------- BEV stage 1: per-(q,z) GEMM into tmp[v][q][o], voxels from contiguous ranges ----------------
__global__ void k_bevg(const float* __restrict__ f, const int* __restrict__ zs,
                       const float* __restrict__ Wt,  // [9][16][16][64][4]
                       float* __restrict__ tmp, int CH){
  int task = blockIdx.x / CH, chunk = blockIdx.x % CH;
  int q = task >> 4, z = task & 15;
  int t = threadIdx.x;   // 64
  const float4* w4 = reinterpret_cast<const float4*>(Wt + (size_t)(((q<<4)+z)<<12)) + t;
  float4 wreg[16];
  #pragma unroll
  for (int c4=0;c4<16;c4++) wreg[c4] = w4[c4*64];
  int s0 = zs[z], c0 = zs[z+1]-s0;
  int s1 = zs[16+z], c1 = zs[17+z]-s1;
  int total = c0 + c1;
  for (int i=chunk; i<total; i+=CH){
    int v = (i<c0) ? s0+i : s1+(i-c0);
    const float4* fr = reinterpret_cast<const float4*>(f + (size_t)v*64);
    float4 a = make_float4(0.f,0.f,0.f,0.f);
    #pragma unroll
    for (int c4=0;c4<16;c4++){
      float4 fv = fr[c4];
      a.x = fmaf(fv.x, wreg[c4].x, a.x);
      a.y = fmaf(fv.y, wreg[c4].y, a.y);
      a.z = fmaf(fv.z, wreg[c4].z, a.z);
      a.w = fmaf(fv.w, wreg[c4].w, a.w);
    }
    tmp[((size_t)v*9+q)*64 + t] = (a.x+a.y)+(a.z+a.w);
  }
}

// ---------------- BEV stage 2: gather tmp into output (1x4 pixel strip per wave) ----------------
// (bbev skipped: per-channel constant cancels in the following BN over (b,y,x))
__global__ void k_bevs(const float* __restrict__ tmp, const int* __restrict__ ccnt,
                       const int* __restrict__ cent, float* __restrict__ outp){
  int blk = xcd_swz(blockIdx.x, gridDim.x);  // 8192 blocks
  int b = blk>>12; int rem = blk&4095; int y = rem>>5; int x0 = (rem&31)<<2;
  int t = threadIdx.x;
  float acc[4] = {0.f,0.f,0.f,0.f};
  #pragma unroll
  for (int dy=-1;dy<=1;dy++){
    int y2 = y+dy;
    if ((unsigned)y2 >= 128u) continue;
    int qb = (dy+1)*3 + 1;
    for (int cx=x0-1; cx<=x0+4; cx++){
      if ((unsigned)cx >= 128u) continue;
      int col = ((b<<7)+y2)*128 + cx;
      int cn = ccnt[col];
      const int* ce = cent + col*16;
      int d0 = cx - x0;
      for (int i=0;i<cn;i++){
        int rid = ce[i]>>4;                 // wave-uniform
        const float* tb = tmp + (size_t)rid*576 + qb*64 + t;
        #pragma unroll
        for (int v=0;v<4;v++){
          int dx = d0 - v;
          if (dx>=-1 && dx<=1) acc[v] += tb[dx*64];
        }
      }
    }
  }
  float4 o4 = make_float4(acc[0],acc[1],acc[2],acc[3]);
  *reinterpret_cast<float4*>(outp + (size_t)b*(256*16384) + (size_t)t*16384 + y*128 + x0) = o4;
}

// ---------------- BEV BN stats (one block per channel) + apply ----------------
__global__ void k_bevstat(const float* __restrict__ outp, const float* __restrict__ g,
                          const float* __restrict__ b, float* __restrict__ mv){
  int ch = blockIdx.x, t = threadIdx.x; // 64 blocks x 256 threads
  float s=0.f, s2=0.f;
  for (int bb=0;bb<2;bb++){
    const float* base = outp + (size_t)bb*(256*16384) + (size_t)ch*16384;
    for (int p=t;p<16384;p+=256){ float v = base[p]; s+=v; s2=fmaf(v,v,s2); }
  }
  __shared__ float ls[256], ls2[256];
  ls[t]=s; ls2[t]=s2; __syncthreads();
  for (int m=128;m;m>>=1){ if (t<m){ ls[t]+=ls[t+m]; ls2[t]+=ls2[t+m]; } __syncthreads(); }
  if (t==0){
    float mean = ls[0]*(1.0f/32768.0f);
    float var  = ls2[0]*(1.0f/32768.0f) - mean*mean;
    float rstd = 1.0f/sqrtf(var+1e-5f);
    float sc = g[ch]*rstd;
    mv[ch*2]=sc; mv[ch*2+1]=b[ch]-mean*sc;
  }
}

__global__ void k_bevbn(float* __restrict__ outp, const float* __restrict__ mv){
  int i = blockIdx.x*256+threadIdx.x; // 2*64*16384
  if (i >= 2*64*16384) return;
  int bb = i>>20; int r = i & ((1<<20)-1);
  int ch = r>>14; int p = r&16383;
  float* a = outp + (size_t)bb*(256*16384) + (size_t)ch*16384 + p;
  float v = fmaf(*a, mv[ch*2], mv[ch*2+1]);
  *a = v>0.f? v:0.f;
}

extern "C" void kernel_launch(void* const* d_in, const int* in_sizes, int n_in,
                              void* d_out, int out_size, void* d_ws, size_t ws_size,
                              hipStream_t stream){
  const float* featR = (const float*)d_in[0];
  const float* featL = (const float*)d_in[1];
  const float* img   = (const float*)d_in[2];
  const float* Win   = (const float*)d_in[3];
  const float* bin_  = (const float*)d_in[4];
  const float* Wconv = (const float*)d_in[5];
  // d_in[6] bconv: cancels in BN
  const float* bng   = (const float*)d_in[7];
  const float* bnb   = (const float*)d_in[8];
  const float* Wimg  = (const float*)d_in[9];
  const float* bimg  = (const float*)d_in[10];
  const float* Wval  = (const float*)d_in[11];
  const float* bval  = (const float*)d_in[12];
  const float* Wgate = (const float*)d_in[13];
  const float* bgate = (const float*)d_in[14];
  const float* Wbev  = (const float*)d_in[15];
  // d_in[16] bbev: cancels in BN
  const float* bntg  = (const float*)d_in[17];
  const float* bntb  = (const float*)d_in[18];
  const int* nbrR    = (const int*)d_in[19];
  const int* nbrL    = (const int*)d_in[20];
  const int* knn0    = (const int*)d_in[21];
  const int* knn1    = (const int*)d_in[22];
  const int* coordsR = (const int*)d_in[23];
  const int* coordsL = (const int*)d_in[24];
  float* outp = (float*)d_out;

  // workspace carve-out (~115 MB); psum aliases tmp (disjoint lifetimes)
  char* w = (char*)d_ws;
  auto alloc = [&](size_t bytes){ char* p = w; w += (bytes + 255) & ~(size_t)255; return p; };
  float* fRa = (float*)alloc((size_t)NRT*64*4);
  float* fLa = (float*)alloc((size_t)NLT*64*4);
  int*   gridR = (int*)alloc((size_t)2*128*128*16*4);
  int*   gridL = (int*)alloc((size_t)2*128*128*16*4);
  float* Wt3 = (float*)alloc((size_t)4*9*16*16*64*4*4);
  float* WcT = (float*)alloc((size_t)12*27*16*64*4*4);
  float* imgfbuf = (float*)alloc(2*64*4);
  float* partial = (float*)alloc((size_t)256*64*2*4);
  float* mv = (float*)alloc(64*2*4);
  int* kmaskR = (int*)alloc((size_t)(NRT/16)*4);
  int* kmaskL = (int*)alloc((size_t)(NLT/16)*4);
  int* ccntR = (int*)alloc((size_t)2*128*128*4);
  int* ccntL = (int*)alloc((size_t)2*128*128*4);
  int* centR = (int*)alloc((size_t)2*128*128*16*4);
  int* centL = (int*)alloc((size_t)2*128*128*16*4);
  int* zsR = (int*)alloc(33*4);
  int* zsL = (int*)alloc(33*4);
  char* big = alloc((size_t)NLT*576*4);           // 92 MB: tmp (bev) / psum (sconv)
  float* tmp  = (float*)big;
  float* psum = (float*)big;                      // 4 * NLT*64 floats = 41 MB < 92 MB
  const size_t PST = (size_t)NLT*64;              // psum split stride

  hipMemsetAsync(gridR, 0xFF, (size_t)2*128*128*16*4, stream);
  hipMemsetAsync(gridL, 0xFF, (size_t)2*128*128*16*4, stream);
  k_grid<<<(NRT+255)/256,256,0,stream>>>(coordsR, NRT, gridR);
  k_grid<<<(NLT+255)/256,256,0,stream>>>(coordsL, NLT, gridL);
  k_colbuild<<<(2*128*128+255)/256,256,0,stream>>>(gridR, ccntR, centR);
  k_colbuild<<<(2*128*128+255)/256,256,0,stream>>>(gridL, ccntL, centL);
  k_zbound<<<(NRT+255)/256,256,0,stream>>>(coordsR, NRT, zsR);
  k_zbound<<<(NLT+255)/256,256,0,stream>>>(coordsL, NLT, zsL);
  k_kmask16<<<((NRT/16)+63)/64,64,0,stream>>>(nbrR, NRT/16, kmaskR);
  k_kmask16<<<((NLT/16)+63)/64,64,0,stream>>>(nbrL, NLT/16, kmaskL);
  k_wt3<<<(4*9*16*16*64*4+255)/256,256,0,stream>>>(Wbev, Wt3);
  k_wc<<<(12*27*16*64*4+255)/256,256,0,stream>>>(Wconv, WcT);

  k_proj<<<(NRT*64+255)/256,256,0,stream>>>(featR, Win,     bin_,    fRa, NRT);
  k_proj<<<(NLT*64+255)/256,256,0,stream>>>(featL, Win+256, bin_+64, fLa, NLT);

  const int CH = 32;   // chunks per (q,z) task in k_bevg
  for (int l=0;l<2;l++){
    // branch R: 3 x (sconv(k-split) -> stats -> fused add+bn+relu back into fRa)
    for (int j=0;j<3;j++){
      const float* Wc = WcT + (size_t)((l*2+0)*3+j)*110592;
      k_sconv<<<NRT/16,256,0,stream>>>(fRa, nbrR, kmaskR, Wc, psum, PST, NRT);
      k_colsum4<<<256,256,0,stream>>>(psum, PST, NRT, partial);
      k_bnfin<<<1,256,0,stream>>>(partial, 256, 1.0f/NRT,
                                  bng + ((l*2+0)*3+j)*64, bnb + ((l*2+0)*3+j)*64, mv);
      k_bnrelu4<<<(NRT*64+255)/256,256,0,stream>>>(psum, PST, mv, fRa, NRT*64);
    }
    // branch L
    for (int j=0;j<3;j++){
      const float* Wc = WcT + (size_t)((l*2+1)*3+j)*110592;
      k_sconv<<<NLT/16,256,0,stream>>>(fLa, nbrL, kmaskL, Wc, psum, PST, NLT);
      k_colsum4<<<256,256,0,stream>>>(psum, PST, NLT, partial);
      k_bnfin<<<1,256,0,stream>>>(partial, 256, 1.0f/NLT,
                                  bng + ((l*2+1)*3+j)*64, bnb + ((l*2+1)*3+j)*64, mv);
      k_bnrelu4<<<(NLT*64+255)/256,256,0,stream>>>(psum, PST, mv, fLa, NLT*64);
    }
    // image gate features for this layer
    k_imgf<<<1,128,0,stream>>>(img, Wimg + (size_t)l*512*64, bimg + l*64, imgfbuf);
    // attention + gated residual (in-place on fL)
    const int* knn = (l==0)? knn0 : knn1;
    int K = (l==0)? 64 : 32;
    k_attn<<<NLT,64,0,stream>>>(fLa, fRa, knn, coordsL,
                                Wval + (size_t)l*4096, bval + l*64,
                                Wgate + (size_t)l*8192, bgate + l*64,
                                imgfbuf, K);
    // BEV R (slab 2l) and BEV L (slab 2l+1)
    {
      float* op = outp + (size_t)(2*l)*64*16384;
      const float* wt = Wt3 + (size_t)(l*2+0)*589824;
      k_bevg<<<144*CH,64,0,stream>>>(fRa, zsR, wt, tmp, CH);
      k_bevs<<<2*128*32,64,0,stream>>>(tmp, ccntR, centR, op);
      k_bevstat<<<64,256,0,stream>>>(op, bntg + (l*2+0)*64, bntb + (l*2+0)*64, mv);
      k_bevbn<<<(2*64*16384+255)/256,256,0,stream>>>(op, mv);
    }
    {
      float* op = outp + (size_t)(2*l+1)*64*16384;
      const float* wt = Wt3 + (size_t)(l*2+1)*589824;
      k_bevg<<<144*CH,64,0,stream>>>(fLa, zsL, wt, tmp, CH);
      k_bevs<<<2*128*32,64,0,stream>>>(tmp, ccntL, centL, op);
      k_bevstat<<<64,256,0,stream>>>(op, bntg + (l*2+1)*64, bntb + (l*2+1)*64, mv);
      k_bevbn<<<(2*64*16384+255)/256,256,0,stream>>>(op, mv);
    }
  }
}